// Round 1
// baseline (761.210 us; speedup 1.0000x reference)
//
#include <hip/hip_runtime.h>
#include <cstddef>
#include <cstdint>

// Problem constants (fixed by reference setup_inputs)
#define DMODEL 256
#define NHEAD  8
#define NLVL   4
#define NPT    4
#define DHEAD  32
#define DFFN   1024
#define SLEN   5440
#define BATCH  4
#define NTOK   (BATCH * SLEN)   // 21760, divisible by 64
#define LN_EPS 1e-5f

// ---------------------------------------------------------------------------
// Generic fp32 GEMM: C[m,n] = act( (A[m,:] (+A2[m,:])) . W[:,n] + bias[n] )
// A: [M,K] row-major, W: [K,N] row-major. 64x64 tile, BK=16, 256 thr, 4x4/thr.
// M%64==0, N%64==0, K%16==0 guaranteed by problem sizes.
// ---------------------------------------------------------------------------
template <bool ADD2, bool RELU>
__global__ __launch_bounds__(256) void gemm_kernel(
    const float* __restrict__ A, const float* __restrict__ A2,
    const float* __restrict__ W, const float* __restrict__ bias,
    float* __restrict__ C, int M, int N, int K)
{
    __shared__ float As[16][68];  // [k][m], pad 68: 16B-aligned rows, 2-way max conflict
    __shared__ float Bs[16][68];  // [k][n]

    const int tid = threadIdx.x;
    const int tx = tid & 15;          // micro-tile col group
    const int ty = tid >> 4;          // micro-tile row group
    const int row0 = blockIdx.y * 64;
    const int col0 = blockIdx.x * 64;

    // A staging: thread -> (row ar, 4 cols at ac4)
    const int ar  = tid >> 2;
    const int ac4 = (tid & 3) << 2;
    // B staging: thread -> (k-row bkr, 4 cols at bc4)
    const int bkr = tid >> 4;
    const int bc4 = (tid & 15) << 2;

    float acc[4][4] = {};

    for (int k0 = 0; k0 < K; k0 += 16) {
        float4 av = *(const float4*)(A + (size_t)(row0 + ar) * K + k0 + ac4);
        if (ADD2) {
            const float4 a2 = *(const float4*)(A2 + (size_t)(row0 + ar) * K + k0 + ac4);
            av.x += a2.x; av.y += a2.y; av.z += a2.z; av.w += a2.w;
        }
        const float4 bv = *(const float4*)(W + (size_t)(k0 + bkr) * N + col0 + bc4);

        __syncthreads();  // previous iteration's LDS reads done
        As[ac4 + 0][ar] = av.x;
        As[ac4 + 1][ar] = av.y;
        As[ac4 + 2][ar] = av.z;
        As[ac4 + 3][ar] = av.w;
        *(float4*)&Bs[bkr][bc4] = bv;
        __syncthreads();

        #pragma unroll
        for (int kk = 0; kk < 16; kk++) {
            const float4 a = *(const float4*)&As[kk][ty << 2];
            const float4 b = *(const float4*)&Bs[kk][tx << 2];
            const float af[4] = {a.x, a.y, a.z, a.w};
            const float bf[4] = {b.x, b.y, b.z, b.w};
            #pragma unroll
            for (int i = 0; i < 4; i++)
                #pragma unroll
                for (int j = 0; j < 4; j++)
                    acc[i][j] = fmaf(af[i], bf[j], acc[i][j]);
        }
    }

    #pragma unroll
    for (int i = 0; i < 4; i++) {
        const int row = row0 + (ty << 2) + i;
        float4 o;
        float* op = &o.x;
        #pragma unroll
        for (int j = 0; j < 4; j++) {
            float v = acc[i][j] + bias[col0 + (tx << 2) + j];
            if (RELU) v = fmaxf(v, 0.f);
            op[j] = v;
        }
        *(float4*)(C + (size_t)row * N + col0 + (tx << 2)) = o;
    }
}

// ---------------------------------------------------------------------------
// MS deformable attention sampling (+ fused softmax over the 16 logits).
// One block per (b,q); 8 groups of 32 lanes, group = head, lane = dh channel.
// value:  [NTOK][256] (col = h*32+dh)
// off:    [NTOK][256] (col = ((h*4+l)*4+p)*2+c)
// logits: [NTOK][128] (col = h*16 + l*4 + p)
// out:    [NTOK][256]
// ---------------------------------------------------------------------------
__global__ __launch_bounds__(256) void msda_sample_kernel(
    const float* __restrict__ value,
    const float* __restrict__ off,
    const float* __restrict__ logits,
    float* __restrict__ out)
{
    const int tid = threadIdx.x;
    const int h  = tid >> 5;
    const int dh = tid & 31;
    const int bq = blockIdx.x;           // 0..NTOK-1
    const int b  = bq / SLEN;
    const int q  = bq - b * SLEN;

    // reference point from the query's own level location (levels are square)
    int rem, Wq;
    if (q < 4096)      { rem = q;        Wq = 64; }
    else if (q < 5120) { rem = q - 4096; Wq = 32; }
    else if (q < 5376) { rem = q - 5120; Wq = 16; }
    else               { rem = q - 5376; Wq = 8;  }
    const int gy = rem / Wq;
    const int gx = rem - gy * Wq;
    const float ref_x = (gx + 0.5f) / (float)Wq;
    const float ref_y = (gy + 0.5f) / (float)Wq;

    // softmax over this head's 16 logits (redundant per lane; L1-broadcast)
    const float* lg = logits + (size_t)bq * 128 + h * 16;
    float lv[16];
    float mx = -1e30f;
    #pragma unroll
    for (int i = 0; i < 16; i++) { lv[i] = lg[i]; mx = fmaxf(mx, lv[i]); }
    float ssum = 0.f;
    #pragma unroll
    for (int i = 0; i < 16; i++) { lv[i] = expf(lv[i] - mx); ssum += lv[i]; }
    const float inv = 1.f / ssum;

    const float* op = off + (size_t)bq * 256 + h * 32;
    const float* vb = value + (size_t)b * SLEN * 256 + h * 32 + dh;

    constexpr int LW[4] = {64, 32, 16, 8};
    constexpr int LS[4] = {0, 4096, 5120, 5376};

    float acc = 0.f;
    #pragma unroll
    for (int l = 0; l < 4; l++) {
        const int   Wl = LW[l];
        const float fW = (float)LW[l];
        const float* vlev = vb + (size_t)LS[l] * 256;
        #pragma unroll
        for (int p = 0; p < 4; p++) {
            const float ox = op[(l * 4 + p) * 2 + 0];
            const float oy = op[(l * 4 + p) * 2 + 1];
            const float aw = lv[l * 4 + p] * inv;
            // mirror reference arithmetic exactly: (ref + off/W)*W - 0.5
            const float X = (ref_x + ox / fW) * fW - 0.5f;
            const float Y = (ref_y + oy / fW) * fW - 0.5f;
            const float x0f = floorf(X), y0f = floorf(Y);
            const float fx = X - x0f, fy = Y - y0f;
            const int x0 = (int)x0f, y0 = (int)y0f;
            #pragma unroll
            for (int dyc = 0; dyc < 2; dyc++) {
                const int yi = y0 + dyc;
                const float wy = dyc ? fy : (1.f - fy);
                const bool vy = (yi >= 0) && (yi < Wl);
                const int yc = min(max(yi, 0), Wl - 1);
                #pragma unroll
                for (int dxc = 0; dxc < 2; dxc++) {
                    const int xi = x0 + dxc;
                    const float wx = dxc ? fx : (1.f - fx);
                    const bool vx = (xi >= 0) && (xi < Wl);
                    const int xc = min(max(xi, 0), Wl - 1);
                    const float wgt = (vx && vy) ? (wx * wy) : 0.f;
                    const float v = vlev[(size_t)(yc * Wl + xc) * 256];
                    acc = fmaf(aw * wgt, v, acc);
                }
            }
        }
    }
    out[(size_t)bq * 256 + h * 32 + dh] = acc;
}

// ---------------------------------------------------------------------------
// Fused residual-add + LayerNorm: out[row,:] = LN(x1+x2)*g + be
// One wave per row (256 cols -> 4 floats/lane), 4 rows per block.
// ---------------------------------------------------------------------------
__global__ __launch_bounds__(256) void ln_kernel(
    const float* __restrict__ x1, const float* __restrict__ x2,
    const float* __restrict__ g, const float* __restrict__ be,
    float* __restrict__ out)
{
    const int lane = threadIdx.x & 63;
    const int wid  = threadIdx.x >> 6;
    const size_t row  = (size_t)blockIdx.x * 4 + wid;
    const size_t base = row * 256 + lane * 4;

    const float4 a = *(const float4*)(x1 + base);
    const float4 b = *(const float4*)(x2 + base);
    const float v0 = a.x + b.x, v1 = a.y + b.y, v2 = a.z + b.z, v3 = a.w + b.w;

    float s  = v0 + v1 + v2 + v3;
    float s2 = v0 * v0 + v1 * v1 + v2 * v2 + v3 * v3;
    #pragma unroll
    for (int o = 32; o > 0; o >>= 1) {
        s  += __shfl_xor(s, o);
        s2 += __shfl_xor(s2, o);
    }
    const float mu  = s * (1.f / 256.f);
    const float var = s2 * (1.f / 256.f) - mu * mu;
    const float r   = rsqrtf(var + LN_EPS);

    const float4 gv = *(const float4*)(g  + lane * 4);
    const float4 bv = *(const float4*)(be + lane * 4);
    float4 o4;
    o4.x = (v0 - mu) * r * gv.x + bv.x;
    o4.y = (v1 - mu) * r * gv.y + bv.y;
    o4.z = (v2 - mu) * r * gv.z + bv.z;
    o4.w = (v3 - mu) * r * gv.w + bv.w;
    *(float4*)(out + base) = o4;
}

// ---------------------------------------------------------------------------
extern "C" void kernel_launch(void* const* d_in, const int* in_sizes, int n_in,
                              void* d_out, int out_size, void* d_ws, size_t ws_size,
                              hipStream_t stream)
{
    const float* src  = (const float*)d_in[0];
    const float* pos  = (const float*)d_in[1];
    // d_in[2] spatial_shapes, d_in[3] level_start_index: static metadata, hard-coded
    const float* Wv   = (const float*)d_in[4];
    const float* bv   = (const float*)d_in[5];
    const float* Woff = (const float*)d_in[6];
    const float* boff = (const float*)d_in[7];
    const float* Wa   = (const float*)d_in[8];
    const float* ba   = (const float*)d_in[9];
    const float* Wo   = (const float*)d_in[10];
    const float* bo   = (const float*)d_in[11];
    const float* W1   = (const float*)d_in[12];
    const float* b1   = (const float*)d_in[13];
    const float* W2   = (const float*)d_in[14];
    const float* b2   = (const float*)d_in[15];
    const float* g1   = (const float*)d_in[16];
    const float* be1  = (const float*)d_in[17];
    const float* g2   = (const float*)d_in[18];
    const float* be2  = (const float*)d_in[19];
    float* out = (float*)d_out;

    // Workspace layout (floats). Total = NTOK*(256*3 + 128 + 1024) = 41,779,200
    // floats = 159.4 MiB. Aliasing: bufOff is reused for src2 (Wo output),
    // bufAO is reused for x (LN1 output), bufV is reused for FFN2 output —
    // all safe because kernels serialize on `stream`.
    float* ws     = (float*)d_ws;
    float* bufV   = ws;                          // value          [NTOK][256]
    float* bufOff = bufV   + (size_t)NTOK * 256; // offsets / src2 [NTOK][256]
    float* bufA   = bufOff + (size_t)NTOK * 256; // attn logits    [NTOK][128]
    float* bufAO  = bufA   + (size_t)NTOK * 128; // attn_out / x   [NTOK][256]
    float* bufH   = bufAO  + (size_t)NTOK * 256; // FFN hidden     [NTOK][1024]

    const dim3 blk(256);
    const int MR = NTOK / 64;  // 340 row-tiles

    // 1. value = src @ Wv + bv
    gemm_kernel<false, false><<<dim3(4, MR), blk, 0, stream>>>(src, nullptr, Wv, bv, bufV, NTOK, 256, 256);
    // 2. off = (src+pos) @ Woff + boff
    gemm_kernel<true, false><<<dim3(4, MR), blk, 0, stream>>>(src, pos, Woff, boff, bufOff, NTOK, 256, 256);
    // 3. attn logits = (src+pos) @ Wa + ba
    gemm_kernel<true, false><<<dim3(2, MR), blk, 0, stream>>>(src, pos, Wa, ba, bufA, NTOK, 128, 256);
    // 4. deformable sampling (+softmax) -> attn_out
    msda_sample_kernel<<<dim3(NTOK), blk, 0, stream>>>(bufV, bufOff, bufA, bufAO);
    // 5. src2 = attn_out @ Wo + bo  (overwrites bufOff — offsets consumed)
    gemm_kernel<false, false><<<dim3(4, MR), blk, 0, stream>>>(bufAO, nullptr, Wo, bo, bufOff, NTOK, 256, 256);
    // 6. x = LN(src + src2) -> bufAO (attn_out consumed)
    ln_kernel<<<dim3(NTOK / 4), blk, 0, stream>>>(src, bufOff, g1, be1, bufAO);
    // 7. h = relu(x @ W1 + b1)
    gemm_kernel<false, true><<<dim3(16, MR), blk, 0, stream>>>(bufAO, nullptr, W1, b1, bufH, NTOK, 1024, 256);
    // 8. t = h @ W2 + b2  (overwrites bufV — value consumed)
    gemm_kernel<false, false><<<dim3(4, MR), blk, 0, stream>>>(bufH, nullptr, W2, b2, bufV, NTOK, 256, 1024);
    // 9. out = LN(x + t)
    ln_kernel<<<dim3(NTOK / 4), blk, 0, stream>>>(bufAO, bufV, g2, be2, out);
}

// Round 2
// 544.822 us; speedup vs baseline: 1.3972x; 1.3972x over previous
//
#include <hip/hip_runtime.h>
#include <cstddef>
#include <cstdint>

// Problem constants (fixed by reference setup_inputs)
#define DMODEL 256
#define NHEAD  8
#define NLVL   4
#define NPT    4
#define DHEAD  32
#define DFFN   1024
#define SLEN   5440
#define BATCH  4
#define NTOK   (BATCH * SLEN)   // 21760 = 170*128
#define NT256  ((size_t)NTOK * 256)
#define LN_EPS 1e-5f

typedef __attribute__((ext_vector_type(4))) float f32x4;
typedef __attribute__((ext_vector_type(8))) short s16x8;

__device__ __forceinline__ unsigned short f2bf(float f) {
    union { float f; unsigned u; } v; v.f = f;
    unsigned u = v.u;
    u += 0x7FFFu + ((u >> 16) & 1u);   // round-to-nearest-even
    return (unsigned short)(u >> 16);
}
__device__ __forceinline__ float bf2f(unsigned short h) {
    union { unsigned u; float f; } v; v.u = ((unsigned)h) << 16;
    return v.f;
}

// ---------------------------------------------------------------------------
// prep: srcB = bf16(src); qB = bf16(src + pos)
// ---------------------------------------------------------------------------
__global__ __launch_bounds__(256) void prep_kernel(
    const float* __restrict__ src, const float* __restrict__ pos,
    unsigned short* __restrict__ srcB, unsigned short* __restrict__ qB)
{
    const size_t i = ((size_t)blockIdx.x * 256 + threadIdx.x) * 4;
    const float4 s = *(const float4*)(src + i);
    const float4 p = *(const float4*)(pos + i);
    ushort4 sb, qb;
    sb.x = f2bf(s.x); sb.y = f2bf(s.y); sb.z = f2bf(s.z); sb.w = f2bf(s.w);
    qb.x = f2bf(s.x + p.x); qb.y = f2bf(s.y + p.y);
    qb.z = f2bf(s.z + p.z); qb.w = f2bf(s.w + p.w);
    *(ushort4*)(srcB + i) = sb;
    *(ushort4*)(qB + i) = qb;
}

// ---------------------------------------------------------------------------
// Weight transpose + bf16 convert: W [K][N] fp32 -> Wt [N][K] bf16.
// 64x64 LDS tile, both sides coalesced. K,N multiples of 64.
// ---------------------------------------------------------------------------
__global__ __launch_bounds__(256) void transpose_bf16_kernel(
    const float* __restrict__ W, unsigned short* __restrict__ Wt, int K, int N)
{
    __shared__ float T[64][65];
    const int k0 = blockIdx.y * 64, n0 = blockIdx.x * 64;
    const int r  = threadIdx.x >> 4;        // 0..15
    const int c4 = (threadIdx.x & 15) * 4;  // 0..60
    #pragma unroll
    for (int rep = 0; rep < 4; rep++) {
        const int k = rep * 16 + r;
        const float4 v = *(const float4*)(W + (size_t)(k0 + k) * N + n0 + c4);
        T[c4 + 0][k] = v.x; T[c4 + 1][k] = v.y;
        T[c4 + 2][k] = v.z; T[c4 + 3][k] = v.w;
    }
    __syncthreads();
    #pragma unroll
    for (int rep = 0; rep < 4; rep++) {
        const int n = rep * 16 + r;
        ushort4 o;
        o.x = f2bf(T[n][c4 + 0]); o.y = f2bf(T[n][c4 + 1]);
        o.z = f2bf(T[n][c4 + 2]); o.w = f2bf(T[n][c4 + 3]);
        *(ushort4*)(Wt + (size_t)(n0 + n) * K + k0 + c4) = o;
    }
}

// ---------------------------------------------------------------------------
// bf16 MFMA GEMM (B-transposed): C[m,n] = act(A[m,:].Bt[n,:] + bias[n])
// A: [M][K] bf16, Bt: [N][K] bf16, bias fp32.
// 128x128 tile, BK=32, 256 threads = 4 waves each computing 64x64 via
// 4x4 grid of mfma_f32_16x16x32_bf16. m92/m97-verified structure.
// ---------------------------------------------------------------------------
#define BM 128
#define BN 128
#define BK 32

template <bool RELU, bool OUTBF16>
__global__ __launch_bounds__(256) void gemm_bt_kernel(
    const unsigned short* __restrict__ A,
    const unsigned short* __restrict__ Bt,
    const float* __restrict__ bias,
    void* __restrict__ Cout, int M, int N, int K)
{
    __shared__ __align__(16) unsigned short sA[BM * BK];  // [m][k], 8 KB
    __shared__ __align__(16) unsigned short sB[BN * BK];  // [n][k], 8 KB

    const int tid  = threadIdx.x;
    const int w    = tid >> 6;
    const int lane = tid & 63;
    const int wm   = (w >> 1) * 64;     // wave row offset in tile
    const int wn   = (w & 1) * 64;      // wave col offset in tile
    const int row0 = blockIdx.y * BM;
    const int col0 = blockIdx.x * BN;

    // staging coords: chunk ca = w*2+i covers rows ca*16..+16 of the tile
    const int sr = lane >> 2;          // 0..15 (row within chunk)
    const int sk = (lane & 3) * 8;     // 0,8,16,24 (k offset)

    const int m16 = lane & 15;
    const int q   = lane >> 4;

    f32x4 acc[4][4];
    #pragma unroll
    for (int i = 0; i < 4; i++)
        #pragma unroll
        for (int j = 0; j < 4; j++)
            acc[i][j] = (f32x4){0.f, 0.f, 0.f, 0.f};

    for (int k0 = 0; k0 < K; k0 += BK) {
        int4 av[2], bv[2];
        #pragma unroll
        for (int i = 0; i < 2; i++) {
            const int ca = w * 2 + i;
            av[i] = *(const int4*)(A  + (size_t)(row0 + ca * 16 + sr) * K + k0 + sk);
            bv[i] = *(const int4*)(Bt + (size_t)(col0 + ca * 16 + sr) * K + k0 + sk);
        }
        __syncthreads();  // previous iteration's LDS reads done
        #pragma unroll
        for (int i = 0; i < 2; i++) {
            const int ca = w * 2 + i;
            *(int4*)&sA[ca * 512 + lane * 8] = av[i];
            *(int4*)&sB[ca * 512 + lane * 8] = bv[i];
        }
        __syncthreads();

        s16x8 af[4], bfr[4];
        #pragma unroll
        for (int i = 0; i < 4; i++)
            af[i] = *(const s16x8*)&sA[(wm + i * 16 + m16) * BK + q * 8];
        #pragma unroll
        for (int j = 0; j < 4; j++)
            bfr[j] = *(const s16x8*)&sB[(wn + j * 16 + m16) * BK + q * 8];

        #pragma unroll
        for (int i = 0; i < 4; i++)
            #pragma unroll
            for (int j = 0; j < 4; j++)
                acc[i][j] = __builtin_amdgcn_mfma_f32_16x16x32_bf16(
                    af[i], bfr[j], acc[i][j], 0, 0, 0);
    }

    // epilogue: D layout col=lane&15, row=(lane>>4)*4+reg  (m89/m91-verified)
    #pragma unroll
    for (int i = 0; i < 4; i++) {
        #pragma unroll
        for (int j = 0; j < 4; j++) {
            const int col = col0 + wn + j * 16 + m16;
            const float bcol = bias[col];
            #pragma unroll
            for (int r = 0; r < 4; r++) {
                const int row = row0 + wm + i * 16 + q * 4 + r;
                float v = acc[i][j][r] + bcol;
                if (RELU) v = fmaxf(v, 0.f);
                if (OUTBF16)
                    ((unsigned short*)Cout)[(size_t)row * N + col] = f2bf(v);
                else
                    ((float*)Cout)[(size_t)row * N + col] = v;
            }
        }
    }
}

// ---------------------------------------------------------------------------
// MS deformable attention sampling (+ fused softmax over the 16 logits).
// One block per (b,q); 8 groups of 32 lanes, group = head, lane = dh channel.
// value: bf16 [NTOK][256]; off fp32 [NTOK][256]; logits fp32 [NTOK][128];
// out: bf16 [NTOK][256]
// ---------------------------------------------------------------------------
__global__ __launch_bounds__(256) void msda_sample_kernel(
    const unsigned short* __restrict__ value,
    const float* __restrict__ off,
    const float* __restrict__ logits,
    unsigned short* __restrict__ out)
{
    const int tid = threadIdx.x;
    const int h  = tid >> 5;
    const int dh = tid & 31;
    const int bq = blockIdx.x;
    const int b  = bq / SLEN;
    const int q  = bq - b * SLEN;

    int rem, Wq;
    if (q < 4096)      { rem = q;        Wq = 64; }
    else if (q < 5120) { rem = q - 4096; Wq = 32; }
    else if (q < 5376) { rem = q - 5120; Wq = 16; }
    else               { rem = q - 5376; Wq = 8;  }
    const int gy = rem / Wq;
    const int gx = rem - gy * Wq;
    const float ref_x = (gx + 0.5f) / (float)Wq;
    const float ref_y = (gy + 0.5f) / (float)Wq;

    const float* lg = logits + (size_t)bq * 128 + h * 16;
    float lv[16];
    float mx = -1e30f;
    #pragma unroll
    for (int i = 0; i < 16; i++) { lv[i] = lg[i]; mx = fmaxf(mx, lv[i]); }
    float ssum = 0.f;
    #pragma unroll
    for (int i = 0; i < 16; i++) { lv[i] = expf(lv[i] - mx); ssum += lv[i]; }
    const float inv = 1.f / ssum;

    const float* op = off + (size_t)bq * 256 + h * 32;
    const unsigned short* vb = value + (size_t)b * SLEN * 256 + h * 32 + dh;

    constexpr int LW[4] = {64, 32, 16, 8};
    constexpr int LS[4] = {0, 4096, 5120, 5376};

    float acc = 0.f;
    #pragma unroll
    for (int l = 0; l < 4; l++) {
        const int   Wl = LW[l];
        const float fW = (float)LW[l];
        const unsigned short* vlev = vb + (size_t)LS[l] * 256;
        #pragma unroll
        for (int p = 0; p < 4; p++) {
            const float ox = op[(l * 4 + p) * 2 + 0];
            const float oy = op[(l * 4 + p) * 2 + 1];
            const float aw = lv[l * 4 + p] * inv;
            const float X = (ref_x + ox / fW) * fW - 0.5f;
            const float Y = (ref_y + oy / fW) * fW - 0.5f;
            const float x0f = floorf(X), y0f = floorf(Y);
            const float fx = X - x0f, fy = Y - y0f;
            const int x0 = (int)x0f, y0 = (int)y0f;
            #pragma unroll
            for (int dyc = 0; dyc < 2; dyc++) {
                const int yi = y0 + dyc;
                const float wy = dyc ? fy : (1.f - fy);
                const bool vy = (yi >= 0) && (yi < Wl);
                const int yc = min(max(yi, 0), Wl - 1);
                #pragma unroll
                for (int dxc = 0; dxc < 2; dxc++) {
                    const int xi = x0 + dxc;
                    const float wx = dxc ? fx : (1.f - fx);
                    const bool vx = (xi >= 0) && (xi < Wl);
                    const int xc = min(max(xi, 0), Wl - 1);
                    const float wgt = (vx && vy) ? (wx * wy) : 0.f;
                    const float v = bf2f(vlev[(size_t)(yc * Wl + xc) * 256]);
                    acc = fmaf(aw * wgt, v, acc);
                }
            }
        }
    }
    out[(size_t)bq * 256 + h * 32 + dh] = f2bf(acc);
}

// ---------------------------------------------------------------------------
// Fused residual-add + LayerNorm. One wave per row, 4 rows/block.
// Optionally also writes a bf16 copy of the output.
// ---------------------------------------------------------------------------
template <bool WB>
__global__ __launch_bounds__(256) void ln_kernel(
    const float* __restrict__ x1, const float* __restrict__ x2,
    const float* __restrict__ g, const float* __restrict__ be,
    float* __restrict__ outf, unsigned short* __restrict__ outb)
{
    const int lane = threadIdx.x & 63;
    const int wid  = threadIdx.x >> 6;
    const size_t row  = (size_t)blockIdx.x * 4 + wid;
    const size_t base = row * 256 + lane * 4;

    const float4 a = *(const float4*)(x1 + base);
    const float4 b = *(const float4*)(x2 + base);
    const float v0 = a.x + b.x, v1 = a.y + b.y, v2 = a.z + b.z, v3 = a.w + b.w;

    float s  = v0 + v1 + v2 + v3;
    float s2 = v0 * v0 + v1 * v1 + v2 * v2 + v3 * v3;
    #pragma unroll
    for (int o = 32; o > 0; o >>= 1) {
        s  += __shfl_xor(s, o);
        s2 += __shfl_xor(s2, o);
    }
    const float mu  = s * (1.f / 256.f);
    const float var = s2 * (1.f / 256.f) - mu * mu;
    const float r   = rsqrtf(var + LN_EPS);

    const float4 gv = *(const float4*)(g  + lane * 4);
    const float4 bv = *(const float4*)(be + lane * 4);
    float4 o4;
    o4.x = (v0 - mu) * r * gv.x + bv.x;
    o4.y = (v1 - mu) * r * gv.y + bv.y;
    o4.z = (v2 - mu) * r * gv.z + bv.z;
    o4.w = (v3 - mu) * r * gv.w + bv.w;
    *(float4*)(outf + base) = o4;
    if (WB) {
        ushort4 ob;
        ob.x = f2bf(o4.x); ob.y = f2bf(o4.y); ob.z = f2bf(o4.z); ob.w = f2bf(o4.w);
        *(ushort4*)(outb + base) = ob;
    }
}

// ---------------------------------------------------------------------------
extern "C" void kernel_launch(void* const* d_in, const int* in_sizes, int n_in,
                              void* d_out, int out_size, void* d_ws, size_t ws_size,
                              hipStream_t stream)
{
    const float* src  = (const float*)d_in[0];
    const float* pos  = (const float*)d_in[1];
    const float* Wv   = (const float*)d_in[4];
    const float* bv   = (const float*)d_in[5];
    const float* Woff = (const float*)d_in[6];
    const float* boff = (const float*)d_in[7];
    const float* Wa   = (const float*)d_in[8];
    const float* ba   = (const float*)d_in[9];
    const float* Wo   = (const float*)d_in[10];
    const float* bo   = (const float*)d_in[11];
    const float* W1   = (const float*)d_in[12];
    const float* b1   = (const float*)d_in[13];
    const float* W2   = (const float*)d_in[14];
    const float* b2   = (const float*)d_in[15];
    const float* g1   = (const float*)d_in[16];
    const float* be1  = (const float*)d_in[17];
    const float* g2   = (const float*)d_in[18];
    const float* be2  = (const float*)d_in[19];
    float* out = (float*)d_out;

    // Workspace layout (~146 MB; previous 159.4 MB layout fit, so safe).
    // Aliasing (stream-serialized):
    //   t (fp32, 22.3MB) overwrites [valB, first half of off] after both dead
    //   xB overwrites attn_out after GEMM-Wo consumed it
    //   src2 overwrites off after sampling consumed it
    char* wsp = (char*)d_ws;
    unsigned short* srcB = (unsigned short*)wsp; wsp += NT256 * 2;
    unsigned short* qB   = (unsigned short*)wsp; wsp += NT256 * 2;
    unsigned short* valB = (unsigned short*)wsp; wsp += NT256 * 2;
    float*          offb = (float*)wsp;          wsp += NT256 * 4;   // off -> src2
    float*          tbuf = (float*)valB;                              // aliases valB+off[0:11MB]
    float*          lgts = (float*)wsp;          wsp += (size_t)NTOK * 128 * 4;
    unsigned short* aoB  = (unsigned short*)wsp; wsp += NT256 * 2;   // attn_out -> xB
    float*          x    = (float*)wsp;          wsp += NT256 * 4;
    unsigned short* h    = (unsigned short*)wsp; wsp += (size_t)NTOK * 1024 * 2;
    unsigned short* WvT  = (unsigned short*)wsp; wsp += 256 * 256 * 2;
    unsigned short* WoffT= (unsigned short*)wsp; wsp += 256 * 256 * 2;
    unsigned short* WaT  = (unsigned short*)wsp; wsp += 128 * 256 * 2;
    unsigned short* WoT  = (unsigned short*)wsp; wsp += 256 * 256 * 2;
    unsigned short* W1T  = (unsigned short*)wsp; wsp += 1024 * 256 * 2;
    unsigned short* W2T  = (unsigned short*)wsp; wsp += 256 * 1024 * 2;

    const dim3 blk(256);

    // prep: bf16 casts of src and src+pos
    prep_kernel<<<dim3(NT256 / 1024), blk, 0, stream>>>(src, pos, srcB, qB);
    // weight transposes (fp32 [K][N] -> bf16 [N][K])
    transpose_bf16_kernel<<<dim3(4, 4),  blk, 0, stream>>>(Wv,   WvT,   256, 256);
    transpose_bf16_kernel<<<dim3(4, 4),  blk, 0, stream>>>(Woff, WoffT, 256, 256);
    transpose_bf16_kernel<<<dim3(2, 4),  blk, 0, stream>>>(Wa,   WaT,   256, 128);
    transpose_bf16_kernel<<<dim3(4, 4),  blk, 0, stream>>>(Wo,   WoT,   256, 256);
    transpose_bf16_kernel<<<dim3(16, 4), blk, 0, stream>>>(W1,   W1T,   256, 1024);
    transpose_bf16_kernel<<<dim3(4, 16), blk, 0, stream>>>(W2,   W2T,   1024, 256);

    const int MR = NTOK / BM;  // 170

    // 1. value = src @ Wv + bv  (bf16 out)
    gemm_bt_kernel<false, true><<<dim3(2, MR), blk, 0, stream>>>(srcB, WvT, bv, valB, NTOK, 256, 256);
    // 2. off = q @ Woff + boff  (fp32 out)
    gemm_bt_kernel<false, false><<<dim3(2, MR), blk, 0, stream>>>(qB, WoffT, boff, offb, NTOK, 256, 256);
    // 3. logits = q @ Wa + ba   (fp32 out)
    gemm_bt_kernel<false, false><<<dim3(1, MR), blk, 0, stream>>>(qB, WaT, ba, lgts, NTOK, 128, 256);
    // 4. sampling -> attn_out (bf16)
    msda_sample_kernel<<<dim3(NTOK), blk, 0, stream>>>(valB, offb, lgts, aoB);
    // 5. src2 = attn_out @ Wo + bo (fp32, overwrites off)
    gemm_bt_kernel<false, false><<<dim3(2, MR), blk, 0, stream>>>(aoB, WoT, bo, offb, NTOK, 256, 256);
    // 6. x = LN(src + src2); also bf16 copy xB (overwrites attn_out)
    ln_kernel<true><<<dim3(NTOK / 4), blk, 0, stream>>>(src, offb, g1, be1, x, aoB);
    // 7. h = relu(x @ W1 + b1) (bf16 out)
    gemm_bt_kernel<true, true><<<dim3(8, MR), blk, 0, stream>>>(aoB, W1T, b1, h, NTOK, 1024, 256);
    // 8. t = h @ W2 + b2 (fp32, overwrites valB/off region)
    gemm_bt_kernel<false, false><<<dim3(2, MR), blk, 0, stream>>>(h, W2T, b2, tbuf, NTOK, 256, 1024);
    // 9. out = LN(x + t)
    ln_kernel<false><<<dim3(NTOK / 4), blk, 0, stream>>>(x, tbuf, g2, be2, out, nullptr);
}

// Round 3
// 509.037 us; speedup vs baseline: 1.4954x; 1.0703x over previous
//
#include <hip/hip_runtime.h>
#include <hip/hip_fp16.h>
#include <cstddef>
#include <cstdint>

// Problem constants (fixed by reference setup_inputs)
#define DMODEL 256
#define NHEAD  8
#define NLVL   4
#define NPT    4
#define DHEAD  32
#define DFFN   1024
#define SLEN   5440
#define BATCH  4
#define NTOK   (BATCH * SLEN)   // 21760 = 170*128
#define NT256  ((size_t)NTOK * 256)
#define LN_EPS 1e-5f

typedef __attribute__((ext_vector_type(4))) float f32x4;
typedef __attribute__((ext_vector_type(8))) short s16x8;

__device__ __forceinline__ unsigned short f2bf(float f) {
    union { float f; unsigned u; } v; v.f = f;
    unsigned u = v.u;
    u += 0x7FFFu + ((u >> 16) & 1u);   // round-to-nearest-even
    return (unsigned short)(u >> 16);
}

// ---------------------------------------------------------------------------
// prep: srcB = bf16(src); qB = bf16(src + pos)
// ---------------------------------------------------------------------------
__global__ __launch_bounds__(256) void prep_kernel(
    const float* __restrict__ src, const float* __restrict__ pos,
    unsigned short* __restrict__ srcB, unsigned short* __restrict__ qB)
{
    const size_t i = ((size_t)blockIdx.x * 256 + threadIdx.x) * 4;
    const float4 s = *(const float4*)(src + i);
    const float4 p = *(const float4*)(pos + i);
    ushort4 sb, qb;
    sb.x = f2bf(s.x); sb.y = f2bf(s.y); sb.z = f2bf(s.z); sb.w = f2bf(s.w);
    qb.x = f2bf(s.x + p.x); qb.y = f2bf(s.y + p.y);
    qb.z = f2bf(s.z + p.z); qb.w = f2bf(s.w + p.w);
    *(ushort4*)(srcB + i) = sb;
    *(ushort4*)(qB + i) = qb;
}

// ---------------------------------------------------------------------------
// Weight transpose + bf16 convert: W [K][N] fp32 -> Wt [N][K] bf16.
// ---------------------------------------------------------------------------
__global__ __launch_bounds__(256) void transpose_bf16_kernel(
    const float* __restrict__ W, unsigned short* __restrict__ Wt, int K, int N)
{
    __shared__ float T[64][65];
    const int k0 = blockIdx.y * 64, n0 = blockIdx.x * 64;
    const int r  = threadIdx.x >> 4;
    const int c4 = (threadIdx.x & 15) * 4;
    #pragma unroll
    for (int rep = 0; rep < 4; rep++) {
        const int k = rep * 16 + r;
        const float4 v = *(const float4*)(W + (size_t)(k0 + k) * N + n0 + c4);
        T[c4 + 0][k] = v.x; T[c4 + 1][k] = v.y;
        T[c4 + 2][k] = v.z; T[c4 + 3][k] = v.w;
    }
    __syncthreads();
    #pragma unroll
    for (int rep = 0; rep < 4; rep++) {
        const int n = rep * 16 + r;
        ushort4 o;
        o.x = f2bf(T[n][c4 + 0]); o.y = f2bf(T[n][c4 + 1]);
        o.z = f2bf(T[n][c4 + 2]); o.w = f2bf(T[n][c4 + 3]);
        *(ushort4*)(Wt + (size_t)(n0 + n) * K + k0 + c4) = o;
    }
}

// ---------------------------------------------------------------------------
// bf16 MFMA GEMM (B-transposed), 128x128 tile, BK=32, 4 waves, 4x4 MFMA/wave.
// OM: output mode 0=f32, 1=bf16, 2=f16
// ---------------------------------------------------------------------------
#define BM 128
#define BN 128
#define BK 32

template <bool RELU, int OM>
__global__ __launch_bounds__(256) void gemm_bt_kernel(
    const unsigned short* __restrict__ A,
    const unsigned short* __restrict__ Bt,
    const float* __restrict__ bias,
    void* __restrict__ Cout, int M, int N, int K)
{
    __shared__ __align__(16) unsigned short sA[BM * BK];
    __shared__ __align__(16) unsigned short sB[BN * BK];

    const int tid  = threadIdx.x;
    const int w    = tid >> 6;
    const int lane = tid & 63;
    const int wm   = (w >> 1) * 64;
    const int wn   = (w & 1) * 64;
    const int row0 = blockIdx.y * BM;
    const int col0 = blockIdx.x * BN;

    const int sr = lane >> 2;
    const int sk = (lane & 3) * 8;
    const int m16 = lane & 15;
    const int q   = lane >> 4;

    f32x4 acc[4][4];
    #pragma unroll
    for (int i = 0; i < 4; i++)
        #pragma unroll
        for (int j = 0; j < 4; j++)
            acc[i][j] = (f32x4){0.f, 0.f, 0.f, 0.f};

    for (int k0 = 0; k0 < K; k0 += BK) {
        int4 av[2], bv[2];
        #pragma unroll
        for (int i = 0; i < 2; i++) {
            const int ca = w * 2 + i;
            av[i] = *(const int4*)(A  + (size_t)(row0 + ca * 16 + sr) * K + k0 + sk);
            bv[i] = *(const int4*)(Bt + (size_t)(col0 + ca * 16 + sr) * K + k0 + sk);
        }
        __syncthreads();
        #pragma unroll
        for (int i = 0; i < 2; i++) {
            const int ca = w * 2 + i;
            *(int4*)&sA[ca * 512 + lane * 8] = av[i];
            *(int4*)&sB[ca * 512 + lane * 8] = bv[i];
        }
        __syncthreads();

        s16x8 af[4], bfr[4];
        #pragma unroll
        for (int i = 0; i < 4; i++)
            af[i] = *(const s16x8*)&sA[(wm + i * 16 + m16) * BK + q * 8];
        #pragma unroll
        for (int j = 0; j < 4; j++)
            bfr[j] = *(const s16x8*)&sB[(wn + j * 16 + m16) * BK + q * 8];

        #pragma unroll
        for (int i = 0; i < 4; i++)
            #pragma unroll
            for (int j = 0; j < 4; j++)
                acc[i][j] = __builtin_amdgcn_mfma_f32_16x16x32_bf16(
                    af[i], bfr[j], acc[i][j], 0, 0, 0);
    }

    #pragma unroll
    for (int i = 0; i < 4; i++) {
        #pragma unroll
        for (int j = 0; j < 4; j++) {
            const int col = col0 + wn + j * 16 + m16;
            const float bcol = bias[col];
            #pragma unroll
            for (int r = 0; r < 4; r++) {
                const int row = row0 + wm + i * 16 + q * 4 + r;
                float v = acc[i][j][r] + bcol;
                if (RELU) v = fmaxf(v, 0.f);
                if (OM == 1)
                    ((unsigned short*)Cout)[(size_t)row * N + col] = f2bf(v);
                else if (OM == 2)
                    ((__half*)Cout)[(size_t)row * N + col] = __float2half(v);
                else
                    ((float*)Cout)[(size_t)row * N + col] = v;
            }
        }
    }
}

// ---------------------------------------------------------------------------
// MSDA meta kernel: one thread per (bq, h, p) point (p = l*4+pp, 16/head).
// Computes softmax weight (16-lane shfl), sampling location, and emits:
//   offs[t] = uint4 of 4 corner BYTE offsets into the value level-plane
//             (level start folded; (idx*256)<<1 = idx<<9)
//   wgt[t]  = 4 fp16 fused weights (aw*wx*wy, 0 if corner invalid), packed
// ---------------------------------------------------------------------------
__global__ __launch_bounds__(256) void msda_meta_kernel(
    const float* __restrict__ off, const float* __restrict__ logits,
    uint4* __restrict__ offs, uint2* __restrict__ wgt)
{
    const int t  = blockIdx.x * 256 + threadIdx.x;   // [0, NTOK*128)
    const int p  = t & 15;
    const int h  = (t >> 4) & 7;
    const int bq = t >> 7;
    const int b  = bq / SLEN;
    const int q  = bq - b * SLEN;

    int rem, Wq;
    if (q < 4096)      { rem = q;        Wq = 64; }
    else if (q < 5120) { rem = q - 4096; Wq = 32; }
    else if (q < 5376) { rem = q - 5120; Wq = 16; }
    else               { rem = q - 5376; Wq = 8;  }
    const int gy = rem / Wq;
    const int gx = rem - gy * Wq;
    const float ref_x = (gx + 0.5f) / (float)Wq;
    const float ref_y = (gy + 0.5f) / (float)Wq;

    // softmax across the 16 points of this (bq,h) — lanes p=0..15 aligned
    const float lg = logits[(size_t)bq * 128 + h * 16 + p];
    float mx = lg;
    #pragma unroll
    for (int m = 1; m < 16; m <<= 1) mx = fmaxf(mx, __shfl_xor(mx, m));
    const float e = expf(lg - mx);
    float s = e;
    #pragma unroll
    for (int m = 1; m < 16; m <<= 1) s += __shfl_xor(s, m);
    const float aw = e / s;

    const float2 o2 = *(const float2*)(off + (size_t)bq * 256 + h * 32 + 2 * p);

    const int l = p >> 2;
    constexpr int LW[4] = {64, 32, 16, 8};
    constexpr int LS[4] = {0, 4096, 5120, 5376};
    const int Wl = LW[l];
    const float fW = (float)Wl;

    // mirror reference arithmetic exactly: (ref + off/W)*W - 0.5
    const float X = (ref_x + o2.x / fW) * fW - 0.5f;
    const float Y = (ref_y + o2.y / fW) * fW - 0.5f;
    const float x0f = floorf(X), y0f = floorf(Y);
    const float fx = X - x0f, fy = Y - y0f;
    const int x0 = (int)x0f, y0 = (int)y0f;

    unsigned bo[4]; __half hw[4];
    #pragma unroll
    for (int dy = 0; dy < 2; dy++) {
        const int yi = y0 + dy;
        const float wy = dy ? fy : (1.f - fy);
        const bool vy = (yi >= 0) && (yi < Wl);
        const int yc = min(max(yi, 0), Wl - 1);
        #pragma unroll
        for (int dx = 0; dx < 2; dx++) {
            const int xi = x0 + dx;
            const float wx = dx ? fx : (1.f - fx);
            const bool vx = (xi >= 0) && (xi < Wl);
            const int xc = min(max(xi, 0), Wl - 1);
            const int c = dy * 2 + dx;
            bo[c] = (unsigned)(LS[l] + yc * Wl + xc) << 9;   // byte offset, 256 halves/row
            hw[c] = __float2half((vx && vy) ? (aw * wx * wy) : 0.f);
        }
    }
    union { __half2 h2; unsigned u; } pk0, pk1;
    pk0.h2 = __halves2half2(hw[0], hw[1]);
    pk1.h2 = __halves2half2(hw[2], hw[3]);
    offs[t] = make_uint4(bo[0], bo[1], bo[2], bo[3]);
    wgt[t]  = make_uint2(pk0.u, pk1.u);
}

// ---------------------------------------------------------------------------
// MSDA gather kernel: block per bq, 8 groups x 32 dh lanes.
// Inner loop: 2 broadcast meta loads + 4x {add, load fp16, fma}.
// ---------------------------------------------------------------------------
__global__ __launch_bounds__(256) void msda_sample_kernel(
    const __half* __restrict__ value,
    const uint4* __restrict__ offs, const uint2* __restrict__ wgt,
    unsigned short* __restrict__ out)
{
    const int tid = threadIdx.x;
    const int h  = tid >> 5;
    const int dh = tid & 31;
    const int bq = blockIdx.x;
    const int b  = bq / SLEN;

    const char* vb = (const char*)(value + (size_t)b * SLEN * 256);
    const unsigned lane_off = (unsigned)(h * 32 + dh) * 2;

    const uint4* po = offs + ((size_t)bq * 8 + h) * 16;
    const uint2* pw = wgt  + ((size_t)bq * 8 + h) * 16;

    float acc = 0.f;
    #pragma unroll
    for (int p = 0; p < 16; p++) {
        const uint4 o4 = po[p];
        const uint2 w2 = pw[p];
        union { unsigned u; __half2 h2; } wa, wb;
        wa.u = w2.x; wb.u = w2.y;
        const float w0 = __low2float(wa.h2),  w1 = __high2float(wa.h2);
        const float w2f = __low2float(wb.h2), w3 = __high2float(wb.h2);
        const float v0 = __half2float(*(const __half*)(vb + (o4.x + lane_off)));
        const float v1 = __half2float(*(const __half*)(vb + (o4.y + lane_off)));
        const float v2 = __half2float(*(const __half*)(vb + (o4.z + lane_off)));
        const float v3 = __half2float(*(const __half*)(vb + (o4.w + lane_off)));
        acc = fmaf(w0, v0, acc);
        acc = fmaf(w1, v1, acc);
        acc = fmaf(w2f, v2, acc);
        acc = fmaf(w3, v3, acc);
    }
    out[(size_t)bq * 256 + h * 32 + dh] = f2bf(acc);
}

// ---------------------------------------------------------------------------
// Fused residual-add + LayerNorm. One wave per row, 4 rows/block.
// ---------------------------------------------------------------------------
template <bool WB>
__global__ __launch_bounds__(256) void ln_kernel(
    const float* __restrict__ x1, const float* __restrict__ x2,
    const float* __restrict__ g, const float* __restrict__ be,
    float* __restrict__ outf, unsigned short* __restrict__ outb)
{
    const int lane = threadIdx.x & 63;
    const int wid  = threadIdx.x >> 6;
    const size_t row  = (size_t)blockIdx.x * 4 + wid;
    const size_t base = row * 256 + lane * 4;

    const float4 a = *(const float4*)(x1 + base);
    const float4 b = *(const float4*)(x2 + base);
    const float v0 = a.x + b.x, v1 = a.y + b.y, v2 = a.z + b.z, v3 = a.w + b.w;

    float s  = v0 + v1 + v2 + v3;
    float s2 = v0 * v0 + v1 * v1 + v2 * v2 + v3 * v3;
    #pragma unroll
    for (int o = 32; o > 0; o >>= 1) {
        s  += __shfl_xor(s, o);
        s2 += __shfl_xor(s2, o);
    }
    const float mu  = s * (1.f / 256.f);
    const float var = s2 * (1.f / 256.f) - mu * mu;
    const float r   = rsqrtf(var + LN_EPS);

    const float4 gv = *(const float4*)(g  + lane * 4);
    const float4 bv = *(const float4*)(be + lane * 4);
    float4 o4;
    o4.x = (v0 - mu) * r * gv.x + bv.x;
    o4.y = (v1 - mu) * r * gv.y + bv.y;
    o4.z = (v2 - mu) * r * gv.z + bv.z;
    o4.w = (v3 - mu) * r * gv.w + bv.w;
    *(float4*)(outf + base) = o4;
    if (WB) {
        ushort4 ob;
        ob.x = f2bf(o4.x); ob.y = f2bf(o4.y); ob.z = f2bf(o4.z); ob.w = f2bf(o4.w);
        *(ushort4*)(outb + base) = ob;
    }
}

// ---------------------------------------------------------------------------
extern "C" void kernel_launch(void* const* d_in, const int* in_sizes, int n_in,
                              void* d_out, int out_size, void* d_ws, size_t ws_size,
                              hipStream_t stream)
{
    const float* src  = (const float*)d_in[0];
    const float* pos  = (const float*)d_in[1];
    const float* Wv   = (const float*)d_in[4];
    const float* bv   = (const float*)d_in[5];
    const float* Woff = (const float*)d_in[6];
    const float* boff = (const float*)d_in[7];
    const float* Wa   = (const float*)d_in[8];
    const float* ba   = (const float*)d_in[9];
    const float* Wo   = (const float*)d_in[10];
    const float* bo   = (const float*)d_in[11];
    const float* W1   = (const float*)d_in[12];
    const float* b1   = (const float*)d_in[13];
    const float* W2   = (const float*)d_in[14];
    const float* b2   = (const float*)d_in[15];
    const float* g1   = (const float*)d_in[16];
    const float* be1  = (const float*)d_in[17];
    const float* g2   = (const float*)d_in[18];
    const float* be2  = (const float*)d_in[19];
    float* out = (float*)d_out;

    // Workspace layout. Aliasing (stream-serialized):
    //   wgt  (22.28MB) aliases srcB+qB  (dead after GEMM3; meta runs after)
    //   offs (44.56MB) aliases h        (h written at FFN1, after sampler)
    //   tbuf (22.28MB) aliases valB+offb(first half) (both dead at FFN2)
    char* wsp = (char*)d_ws;
    unsigned short* srcB = (unsigned short*)wsp; wsp += NT256 * 2;
    unsigned short* qB   = (unsigned short*)wsp; wsp += NT256 * 2;
    __half*         valB = (__half*)wsp;         wsp += NT256 * 2;
    float*          offb = (float*)wsp;          wsp += NT256 * 4;
    float*          tbuf = (float*)valB;
    float*          lgts = (float*)wsp;          wsp += (size_t)NTOK * 128 * 4;
    unsigned short* aoB  = (unsigned short*)wsp; wsp += NT256 * 2;
    float*          x    = (float*)wsp;          wsp += NT256 * 4;
    unsigned short* h    = (unsigned short*)wsp; wsp += (size_t)NTOK * 1024 * 2;
    unsigned short* WvT  = (unsigned short*)wsp; wsp += 256 * 256 * 2;
    unsigned short* WoffT= (unsigned short*)wsp; wsp += 256 * 256 * 2;
    unsigned short* WaT  = (unsigned short*)wsp; wsp += 128 * 256 * 2;
    unsigned short* WoT  = (unsigned short*)wsp; wsp += 256 * 256 * 2;
    unsigned short* W1T  = (unsigned short*)wsp; wsp += 1024 * 256 * 2;
    unsigned short* W2T  = (unsigned short*)wsp; wsp += 256 * 1024 * 2;
    uint2*          wgt  = (uint2*)srcB;   // NTOK*128*8  = 22.28MB
    uint4*          offs = (uint4*)h;      // NTOK*128*16 = 44.56MB

    const dim3 blk(256);

    prep_kernel<<<dim3(NT256 / 1024), blk, 0, stream>>>(src, pos, srcB, qB);
    transpose_bf16_kernel<<<dim3(4, 4),  blk, 0, stream>>>(Wv,   WvT,   256, 256);
    transpose_bf16_kernel<<<dim3(4, 4),  blk, 0, stream>>>(Woff, WoffT, 256, 256);
    transpose_bf16_kernel<<<dim3(2, 4),  blk, 0, stream>>>(Wa,   WaT,   256, 128);
    transpose_bf16_kernel<<<dim3(4, 4),  blk, 0, stream>>>(Wo,   WoT,   256, 256);
    transpose_bf16_kernel<<<dim3(16, 4), blk, 0, stream>>>(W1,   W1T,   256, 1024);
    transpose_bf16_kernel<<<dim3(4, 16), blk, 0, stream>>>(W2,   W2T,   1024, 256);

    const int MR = NTOK / BM;  // 170

    // 1. value = src @ Wv + bv  (fp16 out for sampler)
    gemm_bt_kernel<false, 2><<<dim3(2, MR), blk, 0, stream>>>(srcB, WvT, bv, valB, NTOK, 256, 256);
    // 2. off = q @ Woff + boff  (fp32)
    gemm_bt_kernel<false, 0><<<dim3(2, MR), blk, 0, stream>>>(qB, WoffT, boff, offb, NTOK, 256, 256);
    // 3. logits = q @ Wa + ba   (fp32)
    gemm_bt_kernel<false, 0><<<dim3(1, MR), blk, 0, stream>>>(qB, WaT, ba, lgts, NTOK, 128, 256);
    // 3.5 meta: per-point fused softmax/coords/corner offsets+weights
    msda_meta_kernel<<<dim3(NTOK * 128 / 256), blk, 0, stream>>>(offb, lgts, offs, wgt);
    // 4. sampling gather -> attn_out (bf16)
    msda_sample_kernel<<<dim3(NTOK), blk, 0, stream>>>(valB, offs, wgt, aoB);
    // 5. src2 = attn_out @ Wo + bo (fp32, overwrites offb)
    gemm_bt_kernel<false, 0><<<dim3(2, MR), blk, 0, stream>>>(aoB, WoT, bo, offb, NTOK, 256, 256);
    // 6. x = LN(src + src2); bf16 copy into aoB
    ln_kernel<true><<<dim3(NTOK / 4), blk, 0, stream>>>(src, offb, g1, be1, x, aoB);
    // 7. h = relu(x @ W1 + b1) (bf16; overwrites offs region — consumed)
    gemm_bt_kernel<true, 1><<<dim3(8, MR), blk, 0, stream>>>(aoB, W1T, b1, h, NTOK, 1024, 256);
    // 8. t = h @ W2 + b2 (fp32, overwrites valB region — consumed)
    gemm_bt_kernel<false, 0><<<dim3(2, MR), blk, 0, stream>>>(h, W2T, b2, tbuf, NTOK, 256, 1024);
    // 9. out = LN(x + t)
    ln_kernel<false><<<dim3(NTOK / 4), blk, 0, stream>>>(x, tbuf, g2, be2, out, nullptr);
}

// Round 4
// 431.269 us; speedup vs baseline: 1.7650x; 1.1803x over previous
//
#include <hip/hip_runtime.h>
#include <hip/hip_fp16.h>
#include <cstddef>
#include <cstdint>

// Problem constants (fixed by reference setup_inputs)
#define DMODEL 256
#define NHEAD  8
#define NLVL   4
#define NPT    4
#define DHEAD  32
#define DFFN   1024
#define SLEN   5440
#define BATCH  4
#define NTOK   (BATCH * SLEN)   // 21760 = 170*128
#define NT256  ((size_t)NTOK * 256)
#define LN_EPS 1e-5f

typedef __attribute__((ext_vector_type(4))) float f32x4;
typedef __attribute__((ext_vector_type(8))) short s16x8;

__device__ __forceinline__ unsigned short f2bf(float f) {
    union { float f; unsigned u; } v; v.f = f;
    unsigned u = v.u;
    u += 0x7FFFu + ((u >> 16) & 1u);   // round-to-nearest-even
    return (unsigned short)(u >> 16);
}

// ---------------------------------------------------------------------------
// prep: srcB = bf16(src); qB = bf16(src + pos)
// ---------------------------------------------------------------------------
__global__ __launch_bounds__(256) void prep_kernel(
    const float* __restrict__ src, const float* __restrict__ pos,
    unsigned short* __restrict__ srcB, unsigned short* __restrict__ qB)
{
    const size_t i = ((size_t)blockIdx.x * 256 + threadIdx.x) * 4;
    const float4 s = *(const float4*)(src + i);
    const float4 p = *(const float4*)(pos + i);
    ushort4 sb, qb;
    sb.x = f2bf(s.x); sb.y = f2bf(s.y); sb.z = f2bf(s.z); sb.w = f2bf(s.w);
    qb.x = f2bf(s.x + p.x); qb.y = f2bf(s.y + p.y);
    qb.z = f2bf(s.z + p.z); qb.w = f2bf(s.w + p.w);
    *(ushort4*)(srcB + i) = sb;
    *(ushort4*)(qB + i) = qb;
}

// ---------------------------------------------------------------------------
// All 6 weight transposes in ONE launch. W [K][N] fp32 -> Wt [N][K] bf16.
// 64x64 LDS tile per block; job decoded from blockIdx (184 tiles total).
// ---------------------------------------------------------------------------
__global__ __launch_bounds__(256) void transpose_all_kernel(
    const float* __restrict__ Wv, const float* __restrict__ Woff,
    const float* __restrict__ Wa, const float* __restrict__ Wo,
    const float* __restrict__ W1, const float* __restrict__ W2,
    unsigned short* __restrict__ WvT, unsigned short* __restrict__ WoffT,
    unsigned short* __restrict__ WaT, unsigned short* __restrict__ WoT,
    unsigned short* __restrict__ W1T, unsigned short* __restrict__ W2T)
{
    const int bid = blockIdx.x;
    const float* W; unsigned short* Wt; int K, N, t;
    if (bid < 16)       { W = Wv;   Wt = WvT;   K = 256;  N = 256;  t = bid; }
    else if (bid < 32)  { W = Woff; Wt = WoffT; K = 256;  N = 256;  t = bid - 16; }
    else if (bid < 40)  { W = Wa;   Wt = WaT;   K = 256;  N = 128;  t = bid - 32; }
    else if (bid < 56)  { W = Wo;   Wt = WoT;   K = 256;  N = 256;  t = bid - 40; }
    else if (bid < 120) { W = W1;   Wt = W1T;   K = 256;  N = 1024; t = bid - 56; }
    else                { W = W2;   Wt = W2T;   K = 1024; N = 256;  t = bid - 120; }
    const int ntx = N >> 6;
    const int k0 = (t / ntx) * 64, n0 = (t % ntx) * 64;

    __shared__ float T[64][65];
    const int r  = threadIdx.x >> 4;
    const int c4 = (threadIdx.x & 15) * 4;
    #pragma unroll
    for (int rep = 0; rep < 4; rep++) {
        const int k = rep * 16 + r;
        const float4 v = *(const float4*)(W + (size_t)(k0 + k) * N + n0 + c4);
        T[c4 + 0][k] = v.x; T[c4 + 1][k] = v.y;
        T[c4 + 2][k] = v.z; T[c4 + 3][k] = v.w;
    }
    __syncthreads();
    #pragma unroll
    for (int rep = 0; rep < 4; rep++) {
        const int n = rep * 16 + r;
        ushort4 o;
        o.x = f2bf(T[n][c4 + 0]); o.y = f2bf(T[n][c4 + 1]);
        o.z = f2bf(T[n][c4 + 2]); o.w = f2bf(T[n][c4 + 3]);
        *(ushort4*)(Wt + (size_t)(n0 + n) * K + k0 + c4) = o;
    }
}

// ---------------------------------------------------------------------------
// bf16 MFMA GEMM (B-transposed), 128x128 tile, BK=32, 4 waves, 4x4 MFMA/wave.
// OM: output mode 0=f32, 1=bf16, 2=f16
// ---------------------------------------------------------------------------
#define BM 128
#define BN 128
#define BK 32

template <bool RELU, int OM>
__global__ __launch_bounds__(256) void gemm_bt_kernel(
    const unsigned short* __restrict__ A,
    const unsigned short* __restrict__ Bt,
    const float* __restrict__ bias,
    void* __restrict__ Cout, int M, int N, int K)
{
    __shared__ __align__(16) unsigned short sA[BM * BK];
    __shared__ __align__(16) unsigned short sB[BN * BK];

    const int tid  = threadIdx.x;
    const int w    = tid >> 6;
    const int lane = tid & 63;
    const int wm   = (w >> 1) * 64;
    const int wn   = (w & 1) * 64;
    const int row0 = blockIdx.y * BM;
    const int col0 = blockIdx.x * BN;

    const int sr = lane >> 2;
    const int sk = (lane & 3) * 8;
    const int m16 = lane & 15;
    const int q   = lane >> 4;

    f32x4 acc[4][4];
    #pragma unroll
    for (int i = 0; i < 4; i++)
        #pragma unroll
        for (int j = 0; j < 4; j++)
            acc[i][j] = (f32x4){0.f, 0.f, 0.f, 0.f};

    for (int k0 = 0; k0 < K; k0 += BK) {
        int4 av[2], bv[2];
        #pragma unroll
        for (int i = 0; i < 2; i++) {
            const int ca = w * 2 + i;
            av[i] = *(const int4*)(A  + (size_t)(row0 + ca * 16 + sr) * K + k0 + sk);
            bv[i] = *(const int4*)(Bt + (size_t)(col0 + ca * 16 + sr) * K + k0 + sk);
        }
        __syncthreads();
        #pragma unroll
        for (int i = 0; i < 2; i++) {
            const int ca = w * 2 + i;
            *(int4*)&sA[ca * 512 + lane * 8] = av[i];
            *(int4*)&sB[ca * 512 + lane * 8] = bv[i];
        }
        __syncthreads();

        s16x8 af[4], bfr[4];
        #pragma unroll
        for (int i = 0; i < 4; i++)
            af[i] = *(const s16x8*)&sA[(wm + i * 16 + m16) * BK + q * 8];
        #pragma unroll
        for (int j = 0; j < 4; j++)
            bfr[j] = *(const s16x8*)&sB[(wn + j * 16 + m16) * BK + q * 8];

        #pragma unroll
        for (int i = 0; i < 4; i++)
            #pragma unroll
            for (int j = 0; j < 4; j++)
                acc[i][j] = __builtin_amdgcn_mfma_f32_16x16x32_bf16(
                    af[i], bfr[j], acc[i][j], 0, 0, 0);
    }

    #pragma unroll
    for (int i = 0; i < 4; i++) {
        #pragma unroll
        for (int j = 0; j < 4; j++) {
            const int col = col0 + wn + j * 16 + m16;
            const float bcol = bias[col];
            #pragma unroll
            for (int r = 0; r < 4; r++) {
                const int row = row0 + wm + i * 16 + q * 4 + r;
                float v = acc[i][j][r] + bcol;
                if (RELU) v = fmaxf(v, 0.f);
                if (OM == 1)
                    ((unsigned short*)Cout)[(size_t)row * N + col] = f2bf(v);
                else if (OM == 2)
                    ((__half*)Cout)[(size_t)row * N + col] = __float2half(v);
                else
                    ((float*)Cout)[(size_t)row * N + col] = v;
            }
        }
    }
}

// ---------------------------------------------------------------------------
// MSDA meta kernel: one thread per (bq, h, p). Softmax via 16-lane shfl.
// Emits meta[bq][p][h] = uint4 { idx0|idx1<<16, idx2|idx3<<16,
//                                half2(w0,w1),  half2(w2,w3) }
// idx = global row index into value (level start folded, < 5440 fits u16);
// w = aw*wx*wy fp16, zeroed for invalid corners.
// Layout [bq][p][h]: for a sampler wave (2 tokens x 8 heads) one meta load
// touches 2 cache lines.
// ---------------------------------------------------------------------------
__global__ __launch_bounds__(256) void msda_meta_kernel(
    const float* __restrict__ off, const float* __restrict__ logits,
    uint4* __restrict__ meta)
{
    const int t  = blockIdx.x * 256 + threadIdx.x;   // [0, NTOK*128)
    const int p  = t & 15;
    const int h  = (t >> 4) & 7;
    const int bq = t >> 7;
    const int b  = bq / SLEN;
    const int q  = bq - b * SLEN;

    int rem, Wq;
    if (q < 4096)      { rem = q;        Wq = 64; }
    else if (q < 5120) { rem = q - 4096; Wq = 32; }
    else if (q < 5376) { rem = q - 5120; Wq = 16; }
    else               { rem = q - 5376; Wq = 8;  }
    const int gy = rem / Wq;
    const int gx = rem - gy * Wq;
    const float ref_x = (gx + 0.5f) / (float)Wq;
    const float ref_y = (gy + 0.5f) / (float)Wq;

    // softmax across the 16 points of this (bq,h) — lanes p=0..15 aligned
    const float lg = logits[(size_t)bq * 128 + h * 16 + p];
    float mx = lg;
    #pragma unroll
    for (int m = 1; m < 16; m <<= 1) mx = fmaxf(mx, __shfl_xor(mx, m));
    const float e = expf(lg - mx);
    float s = e;
    #pragma unroll
    for (int m = 1; m < 16; m <<= 1) s += __shfl_xor(s, m);
    const float aw = e / s;

    const float2 o2 = *(const float2*)(off + (size_t)bq * 256 + h * 32 + 2 * p);

    const int l = p >> 2;
    constexpr int LW[4] = {64, 32, 16, 8};
    constexpr int LS[4] = {0, 4096, 5120, 5376};
    const int Wl = LW[l];
    const float fW = (float)Wl;

    // mirror reference arithmetic exactly: (ref + off/W)*W - 0.5
    const float X = (ref_x + o2.x / fW) * fW - 0.5f;
    const float Y = (ref_y + o2.y / fW) * fW - 0.5f;
    const float x0f = floorf(X), y0f = floorf(Y);
    const float fx = X - x0f, fy = Y - y0f;
    const int x0 = (int)x0f, y0 = (int)y0f;

    unsigned idx[4]; __half hw[4];
    #pragma unroll
    for (int dy = 0; dy < 2; dy++) {
        const int yi = y0 + dy;
        const float wy = dy ? fy : (1.f - fy);
        const bool vy = (yi >= 0) && (yi < Wl);
        const int yc = min(max(yi, 0), Wl - 1);
        #pragma unroll
        for (int dx = 0; dx < 2; dx++) {
            const int xi = x0 + dx;
            const float wx = dx ? fx : (1.f - fx);
            const bool vx = (xi >= 0) && (xi < Wl);
            const int xc = min(max(xi, 0), Wl - 1);
            const int c = dy * 2 + dx;
            idx[c] = (unsigned)(LS[l] + yc * Wl + xc);   // < 5440, fits u16
            hw[c] = __float2half((vx && vy) ? (aw * wx * wy) : 0.f);
        }
    }
    union { __half2 h2; unsigned u; } pk0, pk1;
    pk0.h2 = __halves2half2(hw[0], hw[1]);
    pk1.h2 = __halves2half2(hw[2], hw[3]);
    uint4 m;
    m.x = idx[0] | (idx[1] << 16);
    m.y = idx[2] | (idx[3] << 16);
    m.z = pk0.u;
    m.w = pk1.u;
    meta[((size_t)bq * 16 + p) * 8 + h] = m;
}

// ---------------------------------------------------------------------------
// MSDA gather: block = 8 tokens. Lane handles 8 channels (16B) of one head:
// sub = tid&3 (channel chunk), h = (tid>>2)&7, token = tid>>5.
// Per point: 1 meta load (16B broadcast to 4 lanes) + 4x dwordx4 value rows.
// fp16 pk_fma accumulation in 4 point-phase accumulators, fp32 merge.
// ---------------------------------------------------------------------------
__global__ __launch_bounds__(256) void msda_sample_kernel(
    const __half* __restrict__ value, const uint4* __restrict__ meta,
    unsigned short* __restrict__ out)
{
    const int tid = threadIdx.x;
    const int sub = tid & 3;
    const int h   = (tid >> 2) & 7;
    const int t8  = tid >> 5;
    const int bq  = blockIdx.x * 8 + t8;
    const int b   = (blockIdx.x * 8) / SLEN;     // uniform per block (5440%8==0)

    const char* vb = (const char*)value + (size_t)b * SLEN * 512;
    const unsigned laneoff = (unsigned)(h * 64 + sub * 16);
    const uint4* metap = meta + (size_t)bq * 128 + h;   // index with p*8

    __half2 acc[4][4];
    #pragma unroll
    for (int i = 0; i < 4; i++)
        #pragma unroll
        for (int k = 0; k < 4; k++)
            acc[i][k] = __float2half2_rn(0.f);

    for (int g = 0; g < 4; g++) {            // point groups
        #pragma unroll
        for (int pp = 0; pp < 4; pp++) {     // point within group (compile-time)
            const int p = g * 4 + pp;
            const uint4 m = metap[p * 8];
            const unsigned a0 = ((m.x & 0xFFFFu) << 9) + laneoff;
            const unsigned a1 = ((m.x >> 16) << 9) + laneoff;
            const unsigned a2 = ((m.y & 0xFFFFu) << 9) + laneoff;
            const unsigned a3 = ((m.y >> 16) << 9) + laneoff;
            const int4 v0 = *(const int4*)(vb + a0);
            const int4 v1 = *(const int4*)(vb + a1);
            const int4 v2 = *(const int4*)(vb + a2);
            const int4 v3 = *(const int4*)(vb + a3);
            union { unsigned u; __half2 h2; } wz, ww;
            wz.u = m.z; ww.u = m.w;
            const __half2 ws0 = __half2half2(__low2half(wz.h2));
            const __half2 ws1 = __half2half2(__high2half(wz.h2));
            const __half2 ws2 = __half2half2(__low2half(ww.h2));
            const __half2 ws3 = __half2half2(__high2half(ww.h2));
            const __half2* p0 = (const __half2*)&v0;
            const __half2* p1 = (const __half2*)&v1;
            const __half2* p2 = (const __half2*)&v2;
            const __half2* p3 = (const __half2*)&v3;
            #pragma unroll
            for (int k = 0; k < 4; k++) {
                acc[pp][k] = __hfma2(ws0, p0[k], acc[pp][k]);
                acc[pp][k] = __hfma2(ws1, p1[k], acc[pp][k]);
                acc[pp][k] = __hfma2(ws2, p2[k], acc[pp][k]);
                acc[pp][k] = __hfma2(ws3, p3[k], acc[pp][k]);
            }
        }
    }

    // merge the 4 phase accumulators in fp32, pack to bf16 (8 channels = 16B)
    uint4 o;
    unsigned* ou = &o.x;
    #pragma unroll
    for (int k = 0; k < 4; k++) {
        float2 s = {0.f, 0.f};
        #pragma unroll
        for (int i = 0; i < 4; i++) {
            const float2 f = __half22float2(acc[i][k]);
            s.x += f.x; s.y += f.y;
        }
        ou[k] = (unsigned)f2bf(s.x) | ((unsigned)f2bf(s.y) << 16);
    }
    *(uint4*)(out + (size_t)bq * 256 + h * 32 + sub * 8) = o;
}

// ---------------------------------------------------------------------------
// Fused residual-add + LayerNorm. One wave per row, 4 rows/block.
// ---------------------------------------------------------------------------
template <bool WB>
__global__ __launch_bounds__(256) void ln_kernel(
    const float* __restrict__ x1, const float* __restrict__ x2,
    const float* __restrict__ g, const float* __restrict__ be,
    float* __restrict__ outf, unsigned short* __restrict__ outb)
{
    const int lane = threadIdx.x & 63;
    const int wid  = threadIdx.x >> 6;
    const size_t row  = (size_t)blockIdx.x * 4 + wid;
    const size_t base = row * 256 + lane * 4;

    const float4 a = *(const float4*)(x1 + base);
    const float4 b = *(const float4*)(x2 + base);
    const float v0 = a.x + b.x, v1 = a.y + b.y, v2 = a.z + b.z, v3 = a.w + b.w;

    float s  = v0 + v1 + v2 + v3;
    float s2 = v0 * v0 + v1 * v1 + v2 * v2 + v3 * v3;
    #pragma unroll
    for (int o = 32; o > 0; o >>= 1) {
        s  += __shfl_xor(s, o);
        s2 += __shfl_xor(s2, o);
    }
    const float mu  = s * (1.f / 256.f);
    const float var = s2 * (1.f / 256.f) - mu * mu;
    const float r   = rsqrtf(var + LN_EPS);

    const float4 gv = *(const float4*)(g  + lane * 4);
    const float4 bv = *(const float4*)(be + lane * 4);
    float4 o4;
    o4.x = (v0 - mu) * r * gv.x + bv.x;
    o4.y = (v1 - mu) * r * gv.y + bv.y;
    o4.z = (v2 - mu) * r * gv.z + bv.z;
    o4.w = (v3 - mu) * r * gv.w + bv.w;
    *(float4*)(outf + base) = o4;
    if (WB) {
        ushort4 ob;
        ob.x = f2bf(o4.x); ob.y = f2bf(o4.y); ob.z = f2bf(o4.z); ob.w = f2bf(o4.w);
        *(ushort4*)(outb + base) = ob;
    }
}

// ---------------------------------------------------------------------------
extern "C" void kernel_launch(void* const* d_in, const int* in_sizes, int n_in,
                              void* d_out, int out_size, void* d_ws, size_t ws_size,
                              hipStream_t stream)
{
    const float* src  = (const float*)d_in[0];
    const float* pos  = (const float*)d_in[1];
    const float* Wv   = (const float*)d_in[4];
    const float* bv   = (const float*)d_in[5];
    const float* Woff = (const float*)d_in[6];
    const float* boff = (const float*)d_in[7];
    const float* Wa   = (const float*)d_in[8];
    const float* ba   = (const float*)d_in[9];
    const float* Wo   = (const float*)d_in[10];
    const float* bo   = (const float*)d_in[11];
    const float* W1   = (const float*)d_in[12];
    const float* b1   = (const float*)d_in[13];
    const float* W2   = (const float*)d_in[14];
    const float* b2   = (const float*)d_in[15];
    const float* g1   = (const float*)d_in[16];
    const float* be1  = (const float*)d_in[17];
    const float* g2   = (const float*)d_in[18];
    const float* be2  = (const float*)d_in[19];
    float* out = (float*)d_out;

    // Workspace layout. Aliasing (stream-serialized):
    //   meta (44.56MB) aliases h    (h written at FFN1, after sampler consumed meta)
    //   tbuf (22.28MB) aliases valB (+offb head) (both dead at FFN2)
    char* wsp = (char*)d_ws;
    unsigned short* srcB = (unsigned short*)wsp; wsp += NT256 * 2;
    unsigned short* qB   = (unsigned short*)wsp; wsp += NT256 * 2;
    __half*         valB = (__half*)wsp;         wsp += NT256 * 2;
    float*          offb = (float*)wsp;          wsp += NT256 * 4;
    float*          tbuf = (float*)valB;
    float*          lgts = (float*)wsp;          wsp += (size_t)NTOK * 128 * 4;
    unsigned short* aoB  = (unsigned short*)wsp; wsp += NT256 * 2;
    float*          x    = (float*)wsp;          wsp += NT256 * 4;
    unsigned short* h    = (unsigned short*)wsp; wsp += (size_t)NTOK * 1024 * 2;
    unsigned short* WvT  = (unsigned short*)wsp; wsp += 256 * 256 * 2;
    unsigned short* WoffT= (unsigned short*)wsp; wsp += 256 * 256 * 2;
    unsigned short* WaT  = (unsigned short*)wsp; wsp += 128 * 256 * 2;
    unsigned short* WoT  = (unsigned short*)wsp; wsp += 256 * 256 * 2;
    unsigned short* W1T  = (unsigned short*)wsp; wsp += 1024 * 256 * 2;
    unsigned short* W2T  = (unsigned short*)wsp; wsp += 256 * 1024 * 2;
    uint4*          meta = (uint4*)h;            // NTOK*128*16 = 44.56MB

    const dim3 blk(256);

    prep_kernel<<<dim3(NT256 / 1024), blk, 0, stream>>>(src, pos, srcB, qB);
    transpose_all_kernel<<<dim3(184), blk, 0, stream>>>(
        Wv, Woff, Wa, Wo, W1, W2, WvT, WoffT, WaT, WoT, W1T, W2T);

    const int MR = NTOK / BM;  // 170

    // 1. value = src @ Wv + bv  (fp16 out for sampler)
    gemm_bt_kernel<false, 2><<<dim3(2, MR), blk, 0, stream>>>(srcB, WvT, bv, valB, NTOK, 256, 256);
    // 2. off = q @ Woff + boff  (fp32)
    gemm_bt_kernel<false, 0><<<dim3(2, MR), blk, 0, stream>>>(qB, WoffT, boff, offb, NTOK, 256, 256);
    // 3. logits = q @ Wa + ba   (fp32)
    gemm_bt_kernel<false, 0><<<dim3(1, MR), blk, 0, stream>>>(qB, WaT, ba, lgts, NTOK, 128, 256);
    // 3.5 meta: per-point fused softmax/coords -> packed idx+weights
    msda_meta_kernel<<<dim3(NTOK * 128 / 256), blk, 0, stream>>>(offb, lgts, meta);
    // 4. sampling gather -> attn_out (bf16)
    msda_sample_kernel<<<dim3(NTOK / 8), blk, 0, stream>>>(valB, meta, aoB);
    // 5. src2 = attn_out @ Wo + bo (fp32, overwrites offb)
    gemm_bt_kernel<false, 0><<<dim3(2, MR), blk, 0, stream>>>(aoB, WoT, bo, offb, NTOK, 256, 256);
    // 6. x = LN(src + src2); bf16 copy into aoB
    ln_kernel<true><<<dim3(NTOK / 4), blk, 0, stream>>>(src, offb, g1, be1, x, aoB);
    // 7. h = relu(x @ W1 + b1) (bf16; overwrites meta region — consumed)
    gemm_bt_kernel<true, 1><<<dim3(8, MR), blk, 0, stream>>>(aoB, W1T, b1, h, NTOK, 1024, 256);
    // 8. t = h @ W2 + b2 (fp32, overwrites valB region — consumed)
    gemm_bt_kernel<false, 0><<<dim3(2, MR), blk, 0, stream>>>(h, W2T, b2, tbuf, NTOK, 256, 1024);
    // 9. out = LN(x + t)
    ln_kernel<false><<<dim3(NTOK / 4), blk, 0, stream>>>(x, tbuf, g2, be2, out, nullptr);
}

// Round 5
// 340.529 us; speedup vs baseline: 2.2354x; 1.2665x over previous
//
#include <hip/hip_runtime.h>
#include <hip/hip_fp16.h>
#include <cstddef>
#include <cstdint>

// Problem constants (fixed by reference setup_inputs)
#define DMODEL 256
#define NHEAD  8
#define NLVL   4
#define NPT    4
#define DHEAD  32
#define DFFN   1024
#define SLEN   5440
#define BATCH  4
#define NTOK   (BATCH * SLEN)   // 21760 = 170*128
#define NT256  ((size_t)NTOK * 256)
#define LN_EPS 1e-5f

typedef __attribute__((ext_vector_type(4))) float f32x4;
typedef __attribute__((ext_vector_type(8))) short s16x8;

__device__ __forceinline__ unsigned short f2bf(float f) {
    union { float f; unsigned u; } v; v.f = f;
    unsigned u = v.u;
    u += 0x7FFFu + ((u >> 16) & 1u);   // round-to-nearest-even
    return (unsigned short)(u >> 16);
}

// ---------------------------------------------------------------------------
// prep: srcB = bf16(src); qB = bf16(src + pos)
// ---------------------------------------------------------------------------
__global__ __launch_bounds__(256) void prep_kernel(
    const float* __restrict__ src, const float* __restrict__ pos,
    unsigned short* __restrict__ srcB, unsigned short* __restrict__ qB)
{
    const size_t i = ((size_t)blockIdx.x * 256 + threadIdx.x) * 4;
    const float4 s = *(const float4*)(src + i);
    const float4 p = *(const float4*)(pos + i);
    ushort4 sb, qb;
    sb.x = f2bf(s.x); sb.y = f2bf(s.y); sb.z = f2bf(s.z); sb.w = f2bf(s.w);
    qb.x = f2bf(s.x + p.x); qb.y = f2bf(s.y + p.y);
    qb.z = f2bf(s.z + p.z); qb.w = f2bf(s.w + p.w);
    *(ushort4*)(srcB + i) = sb;
    *(ushort4*)(qB + i) = qb;
}

// ---------------------------------------------------------------------------
// All 6 weight transposes in ONE launch. W [K][N] fp32 -> Wt [N][K] bf16.
// ---------------------------------------------------------------------------
__global__ __launch_bounds__(256) void transpose_all_kernel(
    const float* __restrict__ Wv, const float* __restrict__ Woff,
    const float* __restrict__ Wa, const float* __restrict__ Wo,
    const float* __restrict__ W1, const float* __restrict__ W2,
    unsigned short* __restrict__ WvT, unsigned short* __restrict__ WoffT,
    unsigned short* __restrict__ WaT, unsigned short* __restrict__ WoT,
    unsigned short* __restrict__ W1T, unsigned short* __restrict__ W2T)
{
    const int bid = blockIdx.x;
    const float* W; unsigned short* Wt; int K, N, t;
    if (bid < 16)       { W = Wv;   Wt = WvT;   K = 256;  N = 256;  t = bid; }
    else if (bid < 32)  { W = Woff; Wt = WoffT; K = 256;  N = 256;  t = bid - 16; }
    else if (bid < 40)  { W = Wa;   Wt = WaT;   K = 256;  N = 128;  t = bid - 32; }
    else if (bid < 56)  { W = Wo;   Wt = WoT;   K = 256;  N = 256;  t = bid - 40; }
    else if (bid < 120) { W = W1;   Wt = W1T;   K = 256;  N = 1024; t = bid - 56; }
    else                { W = W2;   Wt = W2T;   K = 1024; N = 256;  t = bid - 120; }
    const int ntx = N >> 6;
    const int k0 = (t / ntx) * 64, n0 = (t % ntx) * 64;

    __shared__ float T[64][65];
    const int r  = threadIdx.x >> 4;
    const int c4 = (threadIdx.x & 15) * 4;
    #pragma unroll
    for (int rep = 0; rep < 4; rep++) {
        const int k = rep * 16 + r;
        const float4 v = *(const float4*)(W + (size_t)(k0 + k) * N + n0 + c4);
        T[c4 + 0][k] = v.x; T[c4 + 1][k] = v.y;
        T[c4 + 2][k] = v.z; T[c4 + 3][k] = v.w;
    }
    __syncthreads();
    #pragma unroll
    for (int rep = 0; rep < 4; rep++) {
        const int n = rep * 16 + r;
        ushort4 o;
        o.x = f2bf(T[n][c4 + 0]); o.y = f2bf(T[n][c4 + 1]);
        o.z = f2bf(T[n][c4 + 2]); o.w = f2bf(T[n][c4 + 3]);
        *(ushort4*)(Wt + (size_t)(n0 + n) * K + k0 + c4) = o;
    }
}

// ---------------------------------------------------------------------------
// No-barrier-K-loop bf16 MFMA GEMM.  C[m,n] = act(A[m,:].Bt[n,:] + bias[n])
// A: [M][K] bf16, Bt: [N][K] bf16.
// Per 256-wide K-stage: B-slab (128 cols x 256 k = 64KB) staged once into LDS
// in conflict-free [kc][n][8] layout (2 barriers per STAGE). K-loop has NO
// barriers: A-fragments load DIRECTLY from global (lane's 16B load == MFMA
// A-operand; one 64B line per row per iter), fully unrolled so the compiler
// hoists loads deep. Latency hidden by ILP + 8 waves/CU (2 blocks @ 64KB LDS).
// OM: output mode 0=f32, 1=bf16, 2=f16
// ---------------------------------------------------------------------------
#define BM 128
#define BN 128
#define KSTAGE 256

template <bool RELU, int OM>
__global__ __launch_bounds__(256) void gemm_bs_kernel(
    const unsigned short* __restrict__ A,
    const unsigned short* __restrict__ Bt,
    const float* __restrict__ bias,
    void* __restrict__ Cout, int M, int N, int K)
{
    // [kc][n][8]: element (n,k) of stage at ((k>>3)*128 + n)*8 + (k&7)
    __shared__ __align__(16) unsigned short sB[(KSTAGE / 8) * BN * 8];  // 64 KB

    const int tid  = threadIdx.x;
    const int w    = tid >> 6;
    const int lane = tid & 63;
    const int wm   = (w >> 1) * 64;
    const int wn   = (w & 1) * 64;
    const int row0 = blockIdx.y * BM;
    const int col0 = blockIdx.x * BN;
    const int m16  = lane & 15;
    const int q    = lane >> 4;

    // A fragment base pointers (lane-fixed rows; k advances via imm offsets)
    const unsigned short* aptr[4];
    #pragma unroll
    for (int i = 0; i < 4; i++)
        aptr[i] = A + (size_t)(row0 + wm + i * 16 + m16) * K + q * 8;

    // B staging map: thread -> row sn = tid>>1, k-chunk group skc0 = (tid&1)*16
    const int sn   = tid >> 1;
    const int skc0 = (tid & 1) * 16;
    const unsigned short* bsrc0 = Bt + (size_t)(col0 + sn) * K + skc0 * 8;

    f32x4 acc[4][4];
    #pragma unroll
    for (int i = 0; i < 4; i++)
        #pragma unroll
        for (int j = 0; j < 4; j++)
            acc[i][j] = (f32x4){0.f, 0.f, 0.f, 0.f};

    for (int ks = 0; ks < K; ks += KSTAGE) {
        __syncthreads();   // slab readers from previous stage done (no-op 1st)
        #pragma unroll
        for (int c = 0; c < 16; c++) {
            *(int4*)&sB[((skc0 + c) * BN + sn) * 8] =
                *(const int4*)(bsrc0 + ks + c * 8);
        }
        __syncthreads();

        #pragma unroll
        for (int kk = 0; kk < KSTAGE; kk += 32) {
            const int kc0 = kk >> 3;
            s16x8 af[4], bf[4];
            #pragma unroll
            for (int i = 0; i < 4; i++)
                af[i] = *(const s16x8*)(aptr[i] + ks + kk);
            #pragma unroll
            for (int j = 0; j < 4; j++)
                bf[j] = *(const s16x8*)&sB[((kc0 + q) * BN + wn + j * 16 + m16) * 8];
            #pragma unroll
            for (int i = 0; i < 4; i++)
                #pragma unroll
                for (int j = 0; j < 4; j++)
                    acc[i][j] = __builtin_amdgcn_mfma_f32_16x16x32_bf16(
                        af[i], bf[j], acc[i][j], 0, 0, 0);
        }
    }

    // epilogue: D layout col=lane&15, row=(lane>>4)*4+reg  (m89/m91-verified)
    #pragma unroll
    for (int i = 0; i < 4; i++) {
        #pragma unroll
        for (int j = 0; j < 4; j++) {
            const int col = col0 + wn + j * 16 + m16;
            const float bcol = bias[col];
            #pragma unroll
            for (int r = 0; r < 4; r++) {
                const int row = row0 + wm + i * 16 + q * 4 + r;
                float v = acc[i][j][r] + bcol;
                if (RELU) v = fmaxf(v, 0.f);
                if (OM == 1)
                    ((unsigned short*)Cout)[(size_t)row * N + col] = f2bf(v);
                else if (OM == 2)
                    ((__half*)Cout)[(size_t)row * N + col] = __float2half(v);
                else
                    ((float*)Cout)[(size_t)row * N + col] = v;
            }
        }
    }
}

// ---------------------------------------------------------------------------
// MSDA meta kernel: one thread per (bq, h, p). Softmax via 16-lane shfl.
// meta[bq][p][h] = uint4 { idx0|idx1<<16, idx2|idx3<<16, half2(w0,w1), half2(w2,w3) }
// ---------------------------------------------------------------------------
__global__ __launch_bounds__(256) void msda_meta_kernel(
    const float* __restrict__ off, const float* __restrict__ logits,
    uint4* __restrict__ meta)
{
    const int t  = blockIdx.x * 256 + threadIdx.x;   // [0, NTOK*128)
    const int p  = t & 15;
    const int h  = (t >> 4) & 7;
    const int bq = t >> 7;
    const int b  = bq / SLEN;
    const int q  = bq - b * SLEN;

    int rem, Wq;
    if (q < 4096)      { rem = q;        Wq = 64; }
    else if (q < 5120) { rem = q - 4096; Wq = 32; }
    else if (q < 5376) { rem = q - 5120; Wq = 16; }
    else               { rem = q - 5376; Wq = 8;  }
    const int gy = rem / Wq;
    const int gx = rem - gy * Wq;
    const float ref_x = (gx + 0.5f) / (float)Wq;
    const float ref_y = (gy + 0.5f) / (float)Wq;

    const float lg = logits[(size_t)bq * 128 + h * 16 + p];
    float mx = lg;
    #pragma unroll
    for (int m = 1; m < 16; m <<= 1) mx = fmaxf(mx, __shfl_xor(mx, m));
    const float e = expf(lg - mx);
    float s = e;
    #pragma unroll
    for (int m = 1; m < 16; m <<= 1) s += __shfl_xor(s, m);
    const float aw = e / s;

    const float2 o2 = *(const float2*)(off + (size_t)bq * 256 + h * 32 + 2 * p);

    const int l = p >> 2;
    constexpr int LW[4] = {64, 32, 16, 8};
    constexpr int LS[4] = {0, 4096, 5120, 5376};
    const int Wl = LW[l];
    const float fW = (float)Wl;

    // mirror reference arithmetic exactly: (ref + off/W)*W - 0.5
    const float X = (ref_x + o2.x / fW) * fW - 0.5f;
    const float Y = (ref_y + o2.y / fW) * fW - 0.5f;
    const float x0f = floorf(X), y0f = floorf(Y);
    const float fx = X - x0f, fy = Y - y0f;
    const int x0 = (int)x0f, y0 = (int)y0f;

    unsigned idx[4]; __half hw[4];
    #pragma unroll
    for (int dy = 0; dy < 2; dy++) {
        const int yi = y0 + dy;
        const float wy = dy ? fy : (1.f - fy);
        const bool vy = (yi >= 0) && (yi < Wl);
        const int yc = min(max(yi, 0), Wl - 1);
        #pragma unroll
        for (int dx = 0; dx < 2; dx++) {
            const int xi = x0 + dx;
            const float wx = dx ? fx : (1.f - fx);
            const bool vx = (xi >= 0) && (xi < Wl);
            const int xc = min(max(xi, 0), Wl - 1);
            const int c = dy * 2 + dx;
            idx[c] = (unsigned)(LS[l] + yc * Wl + xc);   // < 5440, fits u16
            hw[c] = __float2half((vx && vy) ? (aw * wx * wy) : 0.f);
        }
    }
    union { __half2 h2; unsigned u; } pk0, pk1;
    pk0.h2 = __halves2half2(hw[0], hw[1]);
    pk1.h2 = __halves2half2(hw[2], hw[3]);
    uint4 m;
    m.x = idx[0] | (idx[1] << 16);
    m.y = idx[2] | (idx[3] << 16);
    m.z = pk0.u;
    m.w = pk1.u;
    meta[((size_t)bq * 16 + p) * 8 + h] = m;
}

// ---------------------------------------------------------------------------
// MSDA gather: block = 8 tokens; lane = 8 channels (16B) of one head.
// ---------------------------------------------------------------------------
__global__ __launch_bounds__(256) void msda_sample_kernel(
    const __half* __restrict__ value, const uint4* __restrict__ meta,
    unsigned short* __restrict__ out)
{
    const int tid = threadIdx.x;
    const int sub = tid & 3;
    const int h   = (tid >> 2) & 7;
    const int t8  = tid >> 5;
    const int bq  = blockIdx.x * 8 + t8;
    const int b   = (blockIdx.x * 8) / SLEN;     // uniform per block (5440%8==0)

    const char* vb = (const char*)value + (size_t)b * SLEN * 512;
    const unsigned laneoff = (unsigned)(h * 64 + sub * 16);
    const uint4* metap = meta + (size_t)bq * 128 + h;   // index with p*8

    __half2 acc[4][4];
    #pragma unroll
    for (int i = 0; i < 4; i++)
        #pragma unroll
        for (int k = 0; k < 4; k++)
            acc[i][k] = __float2half2_rn(0.f);

    for (int g = 0; g < 4; g++) {
        #pragma unroll
        for (int pp = 0; pp < 4; pp++) {
            const int p = g * 4 + pp;
            const uint4 m = metap[p * 8];
            const unsigned a0 = ((m.x & 0xFFFFu) << 9) + laneoff;
            const unsigned a1 = ((m.x >> 16) << 9) + laneoff;
            const unsigned a2 = ((m.y & 0xFFFFu) << 9) + laneoff;
            const unsigned a3 = ((m.y >> 16) << 9) + laneoff;
            const int4 v0 = *(const int4*)(vb + a0);
            const int4 v1 = *(const int4*)(vb + a1);
            const int4 v2 = *(const int4*)(vb + a2);
            const int4 v3 = *(const int4*)(vb + a3);
            union { unsigned u; __half2 h2; } wz, ww;
            wz.u = m.z; ww.u = m.w;
            const __half2 ws0 = __half2half2(__low2half(wz.h2));
            const __half2 ws1 = __half2half2(__high2half(wz.h2));
            const __half2 ws2 = __half2half2(__low2half(ww.h2));
            const __half2 ws3 = __half2half2(__high2half(ww.h2));
            const __half2* p0 = (const __half2*)&v0;
            const __half2* p1 = (const __half2*)&v1;
            const __half2* p2 = (const __half2*)&v2;
            const __half2* p3 = (const __half2*)&v3;
            #pragma unroll
            for (int k = 0; k < 4; k++) {
                acc[pp][k] = __hfma2(ws0, p0[k], acc[pp][k]);
                acc[pp][k] = __hfma2(ws1, p1[k], acc[pp][k]);
                acc[pp][k] = __hfma2(ws2, p2[k], acc[pp][k]);
                acc[pp][k] = __hfma2(ws3, p3[k], acc[pp][k]);
            }
        }
    }

    uint4 o;
    unsigned* ou = &o.x;
    #pragma unroll
    for (int k = 0; k < 4; k++) {
        float2 s = {0.f, 0.f};
        #pragma unroll
        for (int i = 0; i < 4; i++) {
            const float2 f = __half22float2(acc[i][k]);
            s.x += f.x; s.y += f.y;
        }
        ou[k] = (unsigned)f2bf(s.x) | ((unsigned)f2bf(s.y) << 16);
    }
    *(uint4*)(out + (size_t)bq * 256 + h * 32 + sub * 8) = o;
}

// ---------------------------------------------------------------------------
// Fused residual-add + LayerNorm. One wave per row, 4 rows/block.
// ---------------------------------------------------------------------------
template <bool WB>
__global__ __launch_bounds__(256) void ln_kernel(
    const float* __restrict__ x1, const float* __restrict__ x2,
    const float* __restrict__ g, const float* __restrict__ be,
    float* __restrict__ outf, unsigned short* __restrict__ outb)
{
    const int lane = threadIdx.x & 63;
    const int wid  = threadIdx.x >> 6;
    const size_t row  = (size_t)blockIdx.x * 4 + wid;
    const size_t base = row * 256 + lane * 4;

    const float4 a = *(const float4*)(x1 + base);
    const float4 b = *(const float4*)(x2 + base);
    const float v0 = a.x + b.x, v1 = a.y + b.y, v2 = a.z + b.z, v3 = a.w + b.w;

    float s  = v0 + v1 + v2 + v3;
    float s2 = v0 * v0 + v1 * v1 + v2 * v2 + v3 * v3;
    #pragma unroll
    for (int o = 32; o > 0; o >>= 1) {
        s  += __shfl_xor(s, o);
        s2 += __shfl_xor(s2, o);
    }
    const float mu  = s * (1.f / 256.f);
    const float var = s2 * (1.f / 256.f) - mu * mu;
    const float r   = rsqrtf(var + LN_EPS);

    const float4 gv = *(const float4*)(g  + lane * 4);
    const float4 bv = *(const float4*)(be + lane * 4);
    float4 o4;
    o4.x = (v0 - mu) * r * gv.x + bv.x;
    o4.y = (v1 - mu) * r * gv.y + bv.y;
    o4.z = (v2 - mu) * r * gv.z + bv.z;
    o4.w = (v3 - mu) * r * gv.w + bv.w;
    *(float4*)(outf + base) = o4;
    if (WB) {
        ushort4 ob;
        ob.x = f2bf(o4.x); ob.y = f2bf(o4.y); ob.z = f2bf(o4.z); ob.w = f2bf(o4.w);
        *(ushort4*)(outb + base) = ob;
    }
}

// ---------------------------------------------------------------------------
extern "C" void kernel_launch(void* const* d_in, const int* in_sizes, int n_in,
                              void* d_out, int out_size, void* d_ws, size_t ws_size,
                              hipStream_t stream)
{
    const float* src  = (const float*)d_in[0];
    const float* pos  = (const float*)d_in[1];
    const float* Wv   = (const float*)d_in[4];
    const float* bv   = (const float*)d_in[5];
    const float* Woff = (const float*)d_in[6];
    const float* boff = (const float*)d_in[7];
    const float* Wa   = (const float*)d_in[8];
    const float* ba   = (const float*)d_in[9];
    const float* Wo   = (const float*)d_in[10];
    const float* bo   = (const float*)d_in[11];
    const float* W1   = (const float*)d_in[12];
    const float* b1   = (const float*)d_in[13];
    const float* W2   = (const float*)d_in[14];
    const float* b2   = (const float*)d_in[15];
    const float* g1   = (const float*)d_in[16];
    const float* be1  = (const float*)d_in[17];
    const float* g2   = (const float*)d_in[18];
    const float* be2  = (const float*)d_in[19];
    float* out = (float*)d_out;

    // Workspace layout. Aliasing (stream-serialized):
    //   meta (44.56MB) aliases h    (h written at FFN1, after sampler consumed meta)
    //   tbuf (22.28MB) aliases valB (+offb head) (both dead at FFN2)
    char* wsp = (char*)d_ws;
    unsigned short* srcB = (unsigned short*)wsp; wsp += NT256 * 2;
    unsigned short* qB   = (unsigned short*)wsp; wsp += NT256 * 2;
    __half*         valB = (__half*)wsp;         wsp += NT256 * 2;
    float*          offb = (float*)wsp;          wsp += NT256 * 4;
    float*          tbuf = (float*)valB;
    float*          lgts = (float*)wsp;          wsp += (size_t)NTOK * 128 * 4;
    unsigned short* aoB  = (unsigned short*)wsp; wsp += NT256 * 2;
    float*          x    = (float*)wsp;          wsp += NT256 * 4;
    unsigned short* h    = (unsigned short*)wsp; wsp += (size_t)NTOK * 1024 * 2;
    unsigned short* WvT  = (unsigned short*)wsp; wsp += 256 * 256 * 2;
    unsigned short* WoffT= (unsigned short*)wsp; wsp += 256 * 256 * 2;
    unsigned short* WaT  = (unsigned short*)wsp; wsp += 128 * 256 * 2;
    unsigned short* WoT  = (unsigned short*)wsp; wsp += 256 * 256 * 2;
    unsigned short* W1T  = (unsigned short*)wsp; wsp += 1024 * 256 * 2;
    unsigned short* W2T  = (unsigned short*)wsp; wsp += 256 * 1024 * 2;
    uint4*          meta = (uint4*)h;            // NTOK*128*16 = 44.56MB

    const dim3 blk(256);

    prep_kernel<<<dim3(NT256 / 1024), blk, 0, stream>>>(src, pos, srcB, qB);
    transpose_all_kernel<<<dim3(184), blk, 0, stream>>>(
        Wv, Woff, Wa, Wo, W1, W2, WvT, WoffT, WaT, WoT, W1T, W2T);

    const int MR = NTOK / BM;  // 170

    // 1. value = src @ Wv + bv  (fp16 out for sampler)
    gemm_bs_kernel<false, 2><<<dim3(2, MR), blk, 0, stream>>>(srcB, WvT, bv, valB, NTOK, 256, 256);
    // 2. off = q @ Woff + boff  (fp32)
    gemm_bs_kernel<false, 0><<<dim3(2, MR), blk, 0, stream>>>(qB, WoffT, boff, offb, NTOK, 256, 256);
    // 3. logits = q @ Wa + ba   (fp32)
    gemm_bs_kernel<false, 0><<<dim3(1, MR), blk, 0, stream>>>(qB, WaT, ba, lgts, NTOK, 128, 256);
    // 3.5 meta: per-point fused softmax/coords -> packed idx+weights
    msda_meta_kernel<<<dim3(NTOK * 128 / 256), blk, 0, stream>>>(offb, lgts, meta);
    // 4. sampling gather -> attn_out (bf16)
    msda_sample_kernel<<<dim3(NTOK / 8), blk, 0, stream>>>(valB, meta, aoB);
    // 5. src2 = attn_out @ Wo + bo (fp32, overwrites offb)
    gemm_bs_kernel<false, 0><<<dim3(2, MR), blk, 0, stream>>>(aoB, WoT, bo, offb, NTOK, 256, 256);
    // 6. x = LN(src + src2); bf16 copy into aoB
    ln_kernel<true><<<dim3(NTOK / 4), blk, 0, stream>>>(src, offb, g1, be1, x, aoB);
    // 7. h = relu(x @ W1 + b1) (bf16; overwrites meta region — consumed)
    gemm_bs_kernel<true, 1><<<dim3(8, MR), blk, 0, stream>>>(aoB, W1T, b1, h, NTOK, 1024, 256);
    // 8. t = h @ W2 + b2 (fp32, K=1024 -> 4 stages; overwrites valB region)
    gemm_bs_kernel<false, 0><<<dim3(2, MR), blk, 0, stream>>>(h, W2T, b2, tbuf, NTOK, 256, 1024);
    // 9. out = LN(x + t)
    ln_kernel<false><<<dim3(NTOK / 4), blk, 0, stream>>>(x, tbuf, g2, be2, out, nullptr);
}